// Round 1
// baseline (509.239 us; speedup 1.0000x reference)
//
#include <hip/hip_runtime.h>

// ---------------- problem constants ----------------
#define B_    4
#define CI_   2
#define H_    48
#define W_    48
#define T_    96
#define CO_   64
#define KK_   3
#define KS_   48          // temporal kernel size = padding
#define XO_   23
#define NSITE 529         // 23*23
#define TP_   145         // output time steps
#define TT_   160         // padded t' (32 groups * 5)
#define TPAD_ 208         // padded LDS time window (needs 159+47+1+pad)
#define NTAP_ 18          // CI*K*K
#define CHUNK_ 3          // taps per LDS chunk
#define THETA_ 5.4f
#define FODEP_ 48
#define WCAP_  265        // ceil(0.5*529)

// ws layout (floats)
#define WS_WKF 0                      // [18][48][64] = 55296
#define WS_M   55296                  // [4][529][145] = 306820
#define WS_A   (55296 + 306820)       // [4][529][145] int32

// ---------------- kernel: zero output ----------------
__global__ void k_zero(float4* __restrict__ p, int n4) {
    int stride = gridDim.x * blockDim.x;
    for (int i = blockIdx.x * blockDim.x + threadIdx.x; i < n4; i += stride)
        p[i] = make_float4(0.f, 0.f, 0.f, 0.f);
}

// ---------------- kernel: temporal kernel synthesis ----------------
// wkf[tap][kt][o] = kern_raw(47-kt ; weight[o,tap]),
// kern_raw(j;w) = max(0, min(j/16, 1.5w - j/32))
__global__ void k_wk(const float* __restrict__ weight, float* __restrict__ wkf) {
    int idx = blockIdx.x * 256 + threadIdx.x;
    if (idx >= NTAP_ * KS_ * CO_) return;
    int o   = idx & 63;
    int kt  = (idx >> 6) % KS_;
    int tap = idx / (64 * KS_);
    int i  = tap / 9;
    int kx = (tap % 9) / 3;
    int ky = tap % 3;
    float w = weight[((o * CI_ + i) * KK_ + kx) * KK_ + ky];
    float j = (float)(47 - kt);
    float v = fminf(j * (1.0f / 16.0f), 1.5f * w - j * (1.0f / 32.0f));
    wkf[idx] = fmaxf(0.0f, v);
}

// ---------------- float->orderable key helpers ----------------
__device__ __forceinline__ unsigned fkey(float f) {
    unsigned u = __float_as_uint(f);
    return (u & 0x80000000u) ? ~u : (u | 0x80000000u);
}
__device__ __forceinline__ float funkey(unsigned u) {
    unsigned b = (u & 0x80000000u) ? (u ^ 0x80000000u) : ~u;
    return __uint_as_float(b);
}

// ---------------- kernel: conv + channel max/argmax ----------------
// one block per (b, x, y). 256 threads = 8 o-groups (o_tile=8) x 32 t'-groups (t_tile=5)
__launch_bounds__(256, 2)
__global__ void k_conv(const float* __restrict__ in, const float* __restrict__ wkf,
                       const float* __restrict__ bias,
                       float* __restrict__ m_out, int* __restrict__ a_out) {
    __shared__ __align__(16) float s_pad[NTAP_][TPAD_];       // 14976 B
    __shared__ __align__(16) float wk[CHUNK_][KS_][CO_];      // 36864 B
    __shared__ unsigned long long red[8][TT_];                // 10240 B

    int bid = blockIdx.x;
    int b = bid / NSITE;
    int n = bid % NSITE;
    int x = n / XO_;
    int y = n % XO_;
    int tid = threadIdx.x;
    int og = tid & 7;        // o-group: o = og*8 + r
    int tg = tid >> 3;       // t'-group: t' = tg*5 + j
    int t0 = tg * 5;

    // zero the padded window
    for (int q = tid; q < NTAP_ * TPAD_; q += 256)
        ((float*)s_pad)[q] = 0.0f;
    __syncthreads();
    // fill s_pad[tap][48 + t] = in[b, i, 2x+kx, 2y+ky, t]  (96 floats = 24 float4 per tap)
    for (int q = tid; q < NTAP_ * 24; q += 256) {
        int tap = q / 24;
        int f4  = q % 24;
        int i  = tap / 9;
        int kx = (tap % 9) / 3;
        int ky = tap % 3;
        const float4* src = (const float4*)(in +
            ((((size_t)b * CI_ + i) * H_ + (2 * x + kx)) * W_ + (2 * y + ky)) * T_);
        *(float4*)(&s_pad[tap][48 + f4 * 4]) = src[f4];
    }

    float acc[8][5];
#pragma unroll
    for (int r = 0; r < 8; ++r)
#pragma unroll
        for (int j = 0; j < 5; ++j) acc[r][j] = 0.0f;

    // 6 chunks of 3 taps
    for (int c = 0; c < 6; ++c) {
        __syncthreads();
        const float4* src = (const float4*)(wkf + (size_t)c * CHUNK_ * KS_ * CO_);
        for (int q = tid; q < CHUNK_ * KS_ * CO_ / 4; q += 256)
            ((float4*)wk)[q] = src[q];
        __syncthreads();

        for (int tl = 0; tl < CHUNK_; ++tl) {
            const float* srow = s_pad[c * CHUNK_ + tl];
            const float* wrow = &wk[tl][0][og * 8];
            float sv0 = srow[t0 + 0], sv1 = srow[t0 + 1], sv2 = srow[t0 + 2],
                  sv3 = srow[t0 + 3], sv4 = srow[t0 + 4];
#pragma unroll 4
            for (int kt = 0; kt < KS_; ++kt) {
                float4 wa = *(const float4*)(wrow + kt * 64);
                float4 wb = *(const float4*)(wrow + kt * 64 + 4);
                float wreg[8] = {wa.x, wa.y, wa.z, wa.w, wb.x, wb.y, wb.z, wb.w};
#pragma unroll
                for (int r = 0; r < 8; ++r) {
                    acc[r][0] += wreg[r] * sv0;
                    acc[r][1] += wreg[r] * sv1;
                    acc[r][2] += wreg[r] * sv2;
                    acc[r][3] += wreg[r] * sv3;
                    acc[r][4] += wreg[r] * sv4;
                }
                sv0 = sv1; sv1 = sv2; sv2 = sv3; sv3 = sv4;
                sv4 = srow[t0 + kt + 5];
            }
        }
    }

    // epilogue: + bias, local max/argmax over this thread's 8 channels
    float bl[8];
#pragma unroll
    for (int r = 0; r < 8; ++r) bl[r] = bias[og * 8 + r];
#pragma unroll
    for (int j = 0; j < 5; ++j) {
        unsigned long long best = 0;
#pragma unroll
        for (int r = 0; r < 8; ++r) {
            float p = acc[r][j] + bl[r];
            int o = og * 8 + r;
            unsigned long long key =
                ((unsigned long long)fkey(p) << 32) | (unsigned long long)(63 - o);
            if (key > best) best = key;
        }
        red[og][t0 + j] = best;
    }
    __syncthreads();

    // final reduce across 8 o-groups, write m / argmax (layout [b][n][145])
    for (int tp = tid; tp < TP_; tp += 256) {
        unsigned long long best = red[0][tp];
#pragma unroll
        for (int g = 1; g < 8; ++g) {
            unsigned long long k2 = red[g][tp];
            if (k2 > best) best = k2;
        }
        float mv = funkey((unsigned)(best >> 32));
        int ch = 63 - (int)(best & 63ULL);
        size_t off = ((size_t)b * NSITE + n) * TP_ + tp;
        m_out[off] = mv;
        a_out[off] = ch;
    }
}

// ---------------- kernel: sequential winner-takes-all ----------------
// one block per batch, 576 threads (site n = tid, valid if < 529)
__launch_bounds__(576)
__global__ void k_wta(const float* __restrict__ m_in, const int* __restrict__ a_in,
                      float* __restrict__ out) {
    int b = blockIdx.x;
    int tid = threadIdx.x;
    int lane = tid & 63;
    int wid = tid >> 6;                 // 9 waves
    __shared__ int cnts[16];
    __shared__ int tot_s;

    bool site = (tid < NSITE);
    const float* mrow = m_in + ((size_t)b * NSITE + tid) * TP_;
    const int*   arow = a_in + ((size_t)b * NSITE + tid) * TP_;
    int dep = 0;

    for (int t = 0; t < TP_; ++t) {
        unsigned long long ball = __ballot(dep != 0);
        if (lane == 0) cnts[wid] = __popcll(ball);
        __syncthreads();
        if (tid == 0) {
            int s = 0;
#pragma unroll
            for (int w2 = 0; w2 < 9; ++w2) s += cnts[w2];
            tot_s = s;
        }
        __syncthreads();
        int tot = tot_s;
        if (site) {
            bool k_ok = (tot < WCAP_);
            bool spike = k_ok && (dep == 0) && (mrow[t] > THETA_);
            if (spike) {
                int ch = arow[t];
                out[(((size_t)b * CO_ + ch) * NSITE + tid) * TP_ + t] = 1.0f;
                dep = FODEP_ - 1;
            } else {
                dep = (dep > 0) ? (dep - 1) : 0;
            }
        }
    }
}

// ---------------- launcher ----------------
extern "C" void kernel_launch(void* const* d_in, const int* in_sizes, int n_in,
                              void* d_out, int out_size, void* d_ws, size_t ws_size,
                              hipStream_t stream) {
    const float* in     = (const float*)d_in[0];
    const float* weight = (const float*)d_in[1];
    const float* bias   = (const float*)d_in[2];
    float* out = (float*)d_out;

    float* wkf = (float*)d_ws + WS_WKF;
    float* m   = (float*)d_ws + WS_M;
    int*   a   = (int*)((float*)d_ws + WS_A);

    // zero the (mostly-zero) spike output: 4*64*529*145 = 19,636,480 floats
    k_zero<<<2048, 256, 0, stream>>>((float4*)out, 19636480 / 4);
    // temporal kernels
    k_wk<<<(NTAP_ * KS_ * CO_ + 255) / 256, 256, 0, stream>>>(weight, wkf);
    // conv + channel max/argmax
    k_conv<<<B_ * NSITE, 256, 0, stream>>>(in, wkf, bias, m, a);
    // sequential WTA
    k_wta<<<B_, 576, 0, stream>>>(m, a, out);
}